// Round 1
// baseline (2184.235 us; speedup 1.0000x reference)
//
#include <hip/hip_runtime.h>
#include <hip/hip_bf16.h>
#include <math.h>

// Problem constants (fixed by reference)
constexpr int Bz = 2, Sq = 4096, Dm = 768, Hn = 12, Hd = 64;
constexpr int Mrows = Bz * Sq;  // 8192

// ---------------------------------------------------------------------------
// LayerNorm: one block per row of 768, 256 threads (3 elems/thread)
// ---------------------------------------------------------------------------
__global__ __launch_bounds__(256) void ln_kernel(
    const float* __restrict__ x, const float* __restrict__ g,
    const float* __restrict__ b, float* __restrict__ xn) {
  const int row = blockIdx.x;
  const int t = threadIdx.x;
  const float* xr = x + (size_t)row * Dm;
  const float v0 = xr[t], v1 = xr[t + 256], v2 = xr[t + 512];
  float s = v0 + v1 + v2;
  float ss = v0 * v0 + v1 * v1 + v2 * v2;
#pragma unroll
  for (int m = 32; m >= 1; m >>= 1) {
    s += __shfl_xor(s, m);
    ss += __shfl_xor(ss, m);
  }
  __shared__ float red[8];
  const int wid = t >> 6, lane = t & 63;
  if (lane == 0) { red[wid] = s; red[4 + wid] = ss; }
  __syncthreads();
  s = red[0] + red[1] + red[2] + red[3];
  ss = red[4] + red[5] + red[6] + red[7];
  const float mu = s * (1.0f / Dm);
  const float var = ss * (1.0f / Dm) - mu * mu;
  const float rstd = rsqrtf(var + 1e-5f);
  float* xo = xn + (size_t)row * Dm;
  xo[t]       = (v0 - mu) * rstd * g[t]       + b[t];
  xo[t + 256] = (v1 - mu) * rstd * g[t + 256] + b[t + 256];
  xo[t + 512] = (v2 - mu) * rstd * g[t + 512] + b[t + 512];
}

// ---------------------------------------------------------------------------
// Tiled fp32 GEMM: C[M,N] = A[M,K] @ W[K,N] + bias (+ resid)
// BM=BN=64, BK=16, 256 threads, 4x4 micro-tile per thread.
// A staged transposed (As[k][m]) so fragment reads are ds_read_b128.
// ---------------------------------------------------------------------------
template <bool RESID>
__global__ __launch_bounds__(256) void gemm64_kernel(
    const float* __restrict__ A, const float* __restrict__ W,
    const float* __restrict__ bias, const float* __restrict__ resid,
    float* __restrict__ C) {
  __shared__ float As[16][68];
  __shared__ float Bs[16][68];
  const int row0 = blockIdx.x * 64;
  const int col0 = blockIdx.y * 64;
  const int t = threadIdx.x;
  const int tx = t & 15, ty = t >> 4;
  // staging indices
  const int am = t >> 2, ak = (t & 3) * 4;   // A: 64 rows x 4 float4
  const int bk = t >> 4, bn = (t & 15) * 4;  // W: 16 rows x 16 float4
  const float* Aptr = A + (size_t)(row0 + am) * Dm + ak;
  const float* Wptr = W + (size_t)bk * Dm + col0 + bn;

  float acc[4][4] = {};
  for (int kt = 0; kt < Dm; kt += 16) {
    const float4 a4 = *(const float4*)(Aptr + kt);
    const float4 b4 = *(const float4*)(Wptr + (size_t)kt * Dm);
    __syncthreads();  // prior iteration's reads complete
    As[ak + 0][am] = a4.x;
    As[ak + 1][am] = a4.y;
    As[ak + 2][am] = a4.z;
    As[ak + 3][am] = a4.w;
    *(float4*)&Bs[bk][bn] = b4;
    __syncthreads();
#pragma unroll
    for (int k = 0; k < 16; ++k) {
      const float4 av = *(const float4*)&As[k][ty * 4];
      const float4 bv = *(const float4*)&Bs[k][tx * 4];
      const float a[4] = {av.x, av.y, av.z, av.w};
      const float bb[4] = {bv.x, bv.y, bv.z, bv.w};
#pragma unroll
      for (int i = 0; i < 4; ++i)
#pragma unroll
        for (int j = 0; j < 4; ++j)
          acc[i][j] = fmaf(a[i], bb[j], acc[i][j]);
    }
  }
  const int r = row0 + ty * 4, c = col0 + tx * 4;
  const float4 bv = *(const float4*)(bias + c);
#pragma unroll
  for (int i = 0; i < 4; ++i) {
    float4 o;
    o.x = acc[i][0] + bv.x;
    o.y = acc[i][1] + bv.y;
    o.z = acc[i][2] + bv.z;
    o.w = acc[i][3] + bv.w;
    if (RESID) {
      const float4 rv = *(const float4*)(resid + (size_t)(r + i) * Dm + c);
      o.x += rv.x; o.y += rv.y; o.z += rv.z; o.w += rv.w;
    }
    *(float4*)(C + (size_t)(r + i) * Dm + c) = o;
  }
}

// ---------------------------------------------------------------------------
// Flash-style attention, fp32. One block per (q-tile 64, head, batch).
// Q/K staged d-major (transposed) in LDS; P overwrites K buffer; online softmax.
// q,k,v,o are [B,S,D] with head slice at column h*64.
// ---------------------------------------------------------------------------
__global__ __launch_bounds__(256) void attn_kernel(
    const float* __restrict__ q, const float* __restrict__ k,
    const float* __restrict__ v, float* __restrict__ o) {
  __shared__ float Qs[64][68];   // [d][i], pre-scaled by 1/8
  __shared__ float KPs[64][68];  // K phase: [d][j]; P phase: [j][i]
  __shared__ float Vs[64][68];   // [j][c]
  const int q0 = blockIdx.x * 64;
  const int h = blockIdx.y, b = blockIdx.z;
  const size_t base = ((size_t)b * Sq) * Dm + (size_t)h * Hd;
  const int t = threadIdx.x;
  const int tx = t & 15, ty = t >> 4;

  // stage Q transposed + scaled
  {
    const int i = t & 15;
    const int d4 = (t >> 4) * 4;
#pragma unroll
    for (int rr = 0; rr < 4; ++rr) {
      const int row = i + rr * 16;
      const float4 q4 = *(const float4*)(q + base + (size_t)(q0 + row) * Dm + d4);
      Qs[d4 + 0][row] = q4.x * 0.125f;
      Qs[d4 + 1][row] = q4.y * 0.125f;
      Qs[d4 + 2][row] = q4.z * 0.125f;
      Qs[d4 + 3][row] = q4.w * 0.125f;
    }
  }

  float mrow[4] = {-INFINITY, -INFINITY, -INFINITY, -INFINITY};
  float lrow[4] = {0.f, 0.f, 0.f, 0.f};
  float oa[4][4] = {};

  for (int kt = 0; kt < Sq; kt += 64) {
    // load K (transposed dest) and V (straight dest)
    float4 kreg[4], vreg[4];
    const int ik = t & 15;
    const int kd4 = (t >> 4) * 4;
    const int vj = t >> 4;
    const int vc4 = (t & 15) * 4;
#pragma unroll
    for (int rr = 0; rr < 4; ++rr) {
      kreg[rr] = *(const float4*)(k + base + (size_t)(kt + ik + rr * 16) * Dm + kd4);
      vreg[rr] = *(const float4*)(v + base + (size_t)(kt + vj + rr * 16) * Dm + vc4);
    }
    __syncthreads();  // prior PV reads of KPs/Vs done
#pragma unroll
    for (int rr = 0; rr < 4; ++rr) {
      const int j = ik + rr * 16;
      KPs[kd4 + 0][j] = kreg[rr].x;
      KPs[kd4 + 1][j] = kreg[rr].y;
      KPs[kd4 + 2][j] = kreg[rr].z;
      KPs[kd4 + 3][j] = kreg[rr].w;
      *(float4*)&Vs[vj + rr * 16][vc4] = vreg[rr];
    }
    __syncthreads();

    // S = (Q/8) K^T : 4x4 per thread
    float s[4][4] = {};
#pragma unroll 8
    for (int d = 0; d < 64; ++d) {
      const float4 qv = *(const float4*)&Qs[d][ty * 4];
      const float4 kv = *(const float4*)&KPs[d][tx * 4];
      const float a[4] = {qv.x, qv.y, qv.z, qv.w};
      const float bb[4] = {kv.x, kv.y, kv.z, kv.w};
#pragma unroll
      for (int i = 0; i < 4; ++i)
#pragma unroll
        for (int j = 0; j < 4; ++j)
          s[i][j] = fmaf(a[i], bb[j], s[i][j]);
    }

    // online softmax (row groups = 16 consecutive lanes)
#pragma unroll
    for (int r = 0; r < 4; ++r) {
      float tm = fmaxf(fmaxf(s[r][0], s[r][1]), fmaxf(s[r][2], s[r][3]));
      tm = fmaxf(tm, __shfl_xor(tm, 1));
      tm = fmaxf(tm, __shfl_xor(tm, 2));
      tm = fmaxf(tm, __shfl_xor(tm, 4));
      tm = fmaxf(tm, __shfl_xor(tm, 8));
      const float mn = fmaxf(mrow[r], tm);
      const float esc = __expf(mrow[r] - mn);  // exp(-inf)=0 on first tile
      mrow[r] = mn;
      float rs = 0.f;
#pragma unroll
      for (int j = 0; j < 4; ++j) {
        s[r][j] = __expf(s[r][j] - mn);
        rs += s[r][j];
      }
      rs += __shfl_xor(rs, 1);
      rs += __shfl_xor(rs, 2);
      rs += __shfl_xor(rs, 4);
      rs += __shfl_xor(rs, 8);
      lrow[r] = lrow[r] * esc + rs;
#pragma unroll
      for (int j = 0; j < 4; ++j) oa[r][j] *= esc;
    }
    __syncthreads();  // all K-phase reads of KPs done

    // write P transposed: KPs[j][i]
#pragma unroll
    for (int r = 0; r < 4; ++r)
#pragma unroll
      for (int j = 0; j < 4; ++j)
        KPs[tx * 4 + j][ty * 4 + r] = s[r][j];
    __syncthreads();

    // O += P V
#pragma unroll 8
    for (int j = 0; j < 64; ++j) {
      const float4 pv = *(const float4*)&KPs[j][ty * 4];
      const float4 vv = *(const float4*)&Vs[j][tx * 4];
      const float p[4] = {pv.x, pv.y, pv.z, pv.w};
      const float vv4[4] = {vv.x, vv.y, vv.z, vv.w};
#pragma unroll
      for (int i = 0; i < 4; ++i)
#pragma unroll
        for (int c = 0; c < 4; ++c)
          oa[i][c] = fmaf(p[i], vv4[c], oa[i][c]);
    }
  }

  // epilogue: normalize, write [B,S,D] slice
#pragma unroll
  for (int r = 0; r < 4; ++r) {
    const float inv = 1.0f / lrow[r];
    float4 o4;
    o4.x = oa[r][0] * inv;
    o4.y = oa[r][1] * inv;
    o4.z = oa[r][2] * inv;
    o4.w = oa[r][3] * inv;
    *(float4*)(o + base + (size_t)(q0 + ty * 4 + r) * Dm + tx * 4) = o4;
  }
}

// ---------------------------------------------------------------------------
extern "C" void kernel_launch(void* const* d_in, const int* in_sizes, int n_in,
                              void* d_out, int out_size, void* d_ws, size_t ws_size,
                              hipStream_t stream) {
  (void)in_sizes; (void)n_in; (void)out_size; (void)ws_size;
  const float* x  = (const float*)d_in[0];
  const float* Wq = (const float*)d_in[1];
  const float* bq = (const float*)d_in[2];
  const float* Wk = (const float*)d_in[3];
  const float* bk = (const float*)d_in[4];
  const float* Wv = (const float*)d_in[5];
  const float* bv = (const float*)d_in[6];
  const float* Wo = (const float*)d_in[7];
  const float* bo = (const float*)d_in[8];
  const float* lg = (const float*)d_in[9];
  const float* lb = (const float*)d_in[10];
  float* out = (float*)d_out;

  float* ws = (float*)d_ws;
  const size_t n = (size_t)Mrows * Dm;
  float* xn = ws;          // 25.2 MB
  float* qb = ws + n;      // 25.2 MB
  float* kb = ws + 2 * n;  // 25.2 MB
  float* vb = ws + 3 * n;  // 25.2 MB
  float* ab = ws + 4 * n;  // 25.2 MB  (total 125.8 MB of d_ws)

  ln_kernel<<<Mrows, 256, 0, stream>>>(x, lg, lb, xn);
  const dim3 gg(Mrows / 64, Dm / 64);
  gemm64_kernel<false><<<gg, 256, 0, stream>>>(xn, Wq, bq, nullptr, qb);
  gemm64_kernel<false><<<gg, 256, 0, stream>>>(xn, Wk, bk, nullptr, kb);
  gemm64_kernel<false><<<gg, 256, 0, stream>>>(xn, Wv, bv, nullptr, vb);
  attn_kernel<<<dim3(Sq / 64, Hn, Bz), 256, 0, stream>>>(qb, kb, vb, ab);
  gemm64_kernel<true><<<gg, 256, 0, stream>>>(ab, Wo, bo, x, out);
}

// Round 2
// 932.707 us; speedup vs baseline: 2.3418x; 2.3418x over previous
//
#include <hip/hip_runtime.h>
#include <hip/hip_bf16.h>
#include <math.h>

// Problem constants (fixed by reference)
constexpr int Bz = 2, Sq = 4096, Dm = 768, Hn = 12, Hd = 64;
constexpr int Mrows = Bz * Sq;  // 8192

typedef short bf16x8 __attribute__((ext_vector_type(8)));
typedef short s16x4 __attribute__((ext_vector_type(4)));
typedef float f32x4 __attribute__((ext_vector_type(4)));

__device__ __forceinline__ short f2bf(float f) {
  unsigned u = __builtin_bit_cast(unsigned, f);
  u += 0x7fffu + ((u >> 16) & 1u);  // round-to-nearest-even
  return (short)(u >> 16);
}

// ---------------------------------------------------------------------------
// LayerNorm: one block per row of 768, 256 threads (3 elems/thread). fp32 out.
// ---------------------------------------------------------------------------
__global__ __launch_bounds__(256) void ln_kernel(
    const float* __restrict__ x, const float* __restrict__ g,
    const float* __restrict__ b, float* __restrict__ xn) {
  const int row = blockIdx.x;
  const int t = threadIdx.x;
  const float* xr = x + (size_t)row * Dm;
  const float v0 = xr[t], v1 = xr[t + 256], v2 = xr[t + 512];
  float s = v0 + v1 + v2;
  float ss = v0 * v0 + v1 * v1 + v2 * v2;
#pragma unroll
  for (int m = 32; m >= 1; m >>= 1) {
    s += __shfl_xor(s, m);
    ss += __shfl_xor(ss, m);
  }
  __shared__ float red[8];
  const int wid = t >> 6, lane = t & 63;
  if (lane == 0) { red[wid] = s; red[4 + wid] = ss; }
  __syncthreads();
  s = red[0] + red[1] + red[2] + red[3];
  ss = red[4] + red[5] + red[6] + red[7];
  const float mu = s * (1.0f / Dm);
  const float var = ss * (1.0f / Dm) - mu * mu;
  const float rstd = rsqrtf(var + 1e-5f);
  float* xo = xn + (size_t)row * Dm;
  xo[t]       = (v0 - mu) * rstd * g[t]       + b[t];
  xo[t + 256] = (v1 - mu) * rstd * g[t + 256] + b[t + 256];
  xo[t + 512] = (v2 - mu) * rstd * g[t + 512] + b[t + 512];
}

// ---------------------------------------------------------------------------
// Tiled fp32 GEMM: C[M,N] = A[M,K] @ W[K,N] + bias (+ resid).
// OT=short -> bf16 output (for QKV feeding the MFMA attention).
// ---------------------------------------------------------------------------
template <typename OT, bool RESID>
__global__ __launch_bounds__(256) void gemm64_kernel(
    const float* __restrict__ A, const float* __restrict__ W,
    const float* __restrict__ bias, const float* __restrict__ resid,
    OT* __restrict__ C) {
  __shared__ float As[16][68];
  __shared__ float Bs[16][68];
  const int row0 = blockIdx.x * 64;
  const int col0 = blockIdx.y * 64;
  const int t = threadIdx.x;
  const int tx = t & 15, ty = t >> 4;
  const int am = t >> 2, ak = (t & 3) * 4;   // A: 64 rows x 4 float4
  const int bk = t >> 4, bn = (t & 15) * 4;  // W: 16 rows x 16 float4
  const float* Aptr = A + (size_t)(row0 + am) * Dm + ak;
  const float* Wptr = W + (size_t)bk * Dm + col0 + bn;

  float acc[4][4] = {};
  for (int kt = 0; kt < Dm; kt += 16) {
    const float4 a4 = *(const float4*)(Aptr + kt);
    const float4 b4 = *(const float4*)(Wptr + (size_t)kt * Dm);
    __syncthreads();
    As[ak + 0][am] = a4.x;
    As[ak + 1][am] = a4.y;
    As[ak + 2][am] = a4.z;
    As[ak + 3][am] = a4.w;
    *(float4*)&Bs[bk][bn] = b4;
    __syncthreads();
#pragma unroll
    for (int k = 0; k < 16; ++k) {
      const float4 av = *(const float4*)&As[k][ty * 4];
      const float4 bv = *(const float4*)&Bs[k][tx * 4];
      const float a[4] = {av.x, av.y, av.z, av.w};
      const float bb[4] = {bv.x, bv.y, bv.z, bv.w};
#pragma unroll
      for (int i = 0; i < 4; ++i)
#pragma unroll
        for (int j = 0; j < 4; ++j)
          acc[i][j] = fmaf(a[i], bb[j], acc[i][j]);
    }
  }
  const int r = row0 + ty * 4, c = col0 + tx * 4;
  const float4 bv = *(const float4*)(bias + c);
  const float bb[4] = {bv.x, bv.y, bv.z, bv.w};
#pragma unroll
  for (int i = 0; i < 4; ++i) {
    float o[4];
#pragma unroll
    for (int j = 0; j < 4; ++j) o[j] = acc[i][j] + bb[j];
    if (RESID) {
      const float4 rv = *(const float4*)(resid + (size_t)(r + i) * Dm + c);
      o[0] += rv.x; o[1] += rv.y; o[2] += rv.z; o[3] += rv.w;
    }
    if constexpr (sizeof(OT) == 2) {
      s16x4 pk;
#pragma unroll
      for (int j = 0; j < 4; ++j) pk[j] = f2bf(o[j]);
      *(s16x4*)((short*)C + (size_t)(r + i) * Dm + c) = pk;
    } else {
      float4 o4 = {o[0], o[1], o[2], o[3]};
      *(float4*)((float*)C + (size_t)(r + i) * Dm + c) = o4;
    }
  }
}

// ---------------------------------------------------------------------------
// V transpose: vb [B,S,768] bf16 -> vt [B,H,64,S] bf16 (kv-contiguous rows).
// ---------------------------------------------------------------------------
__global__ __launch_bounds__(256) void vtrans_kernel(
    const short* __restrict__ vb, short* __restrict__ vt) {
  __shared__ short T[64][72];
  const int kv0 = blockIdx.x * 64;
  const int h = blockIdx.y, b = blockIdx.z;
  const int t = threadIdx.x;
  const size_t ib = ((size_t)b * Sq) * Dm + (size_t)h * Hd;
  const size_t ob = ((size_t)(b * Hn + h) * Hd) * Sq;
#pragma unroll
  for (int cc = 0; cc < 2; ++cc) {
    const int c = t + cc * 256;
    const int row = c >> 3, c8 = c & 7;
    const bf16x8 vv = *(const bf16x8*)(vb + ib + (size_t)(kv0 + row) * Dm + c8 * 8);
#pragma unroll
    for (int e = 0; e < 8; ++e) T[c8 * 8 + e][row] = vv[e];
  }
  __syncthreads();
#pragma unroll
  for (int cc = 0; cc < 2; ++cc) {
    const int c = t + cc * 256;
    const int d = c >> 3, c8 = c & 7;
    *(bf16x8*)(vt + ob + (size_t)d * Sq + kv0 + c8 * 8) = *(const bf16x8*)&T[d][c8 * 8];
  }
}

// ---------------------------------------------------------------------------
// Flash attention with bf16 MFMA (16x16x32), fp32 online softmax.
// Block: 256 thr = 4 waves; Q tile 64 rows (16/wave); K/V tile 64.
// qg,kg: bf16 [B,S,768] head slice at h*64. vt: bf16 [B,H,64,S]. o: fp32 [B,S,768].
// MFMA layouts (16x16x32): A lane l: row=l&15, k=(l>>4)*8+e (8 contig).
// B lane l: col=l&15, k=(l>>4)*8+e. D lane l: col=l&15, row=(l>>4)*4+reg.
// ---------------------------------------------------------------------------
__global__ __launch_bounds__(256) void attn_mfma_kernel(
    const short* __restrict__ qg, const short* __restrict__ kg,
    const short* __restrict__ vt, float* __restrict__ o) {
  __shared__ short Ks[64][72];      // [kv][d]   (B operand of QK^T)
  __shared__ short Vs[64][72];      // [d][kv]   (B operand of PV)
  __shared__ short Ps[4][16][72];   // wave-private P tiles [qrow][kv]
  const int q0 = blockIdx.x * 64;
  const int h = blockIdx.y, b = blockIdx.z;
  const size_t qkbase = ((size_t)b * Sq) * Dm + (size_t)h * Hd;
  const size_t vbase = ((size_t)(b * Hn + h) * Hd) * Sq;
  const int t = threadIdx.x;
  const int w = t >> 6, l = t & 63;
  const int lr = l & 15, lg = l >> 4;

  // Q A-fragments, hoisted: rows q0 + w*16 + lr, k-slices lg*8 (+32)
  bf16x8 aq0, aq1;
  {
    const short* qp = qg + qkbase + (size_t)(q0 + w * 16 + lr) * Dm + lg * 8;
    aq0 = *(const bf16x8*)qp;
    aq1 = *(const bf16x8*)(qp + 32);
  }

  float mrow[4] = {-INFINITY, -INFINITY, -INFINITY, -INFINITY};
  float lrow[4] = {0.f, 0.f, 0.f, 0.f};
  f32x4 oacc[4] = {};  // d-tiles; lane holds col=nt*16+lr, rows lg*4+r

  constexpr float SC = 0.18033688011112042f;  // (1/8) * log2(e)

  for (int kt = 0; kt < Sq; kt += 64) {
    // global loads for this tile (issued before barrier to overlap prior PV)
    const int c0 = t, c1 = t + 256;
    const bf16x8 kr0 = *(const bf16x8*)(kg + qkbase + (size_t)(kt + (c0 >> 3)) * Dm + (c0 & 7) * 8);
    const bf16x8 kr1 = *(const bf16x8*)(kg + qkbase + (size_t)(kt + (c1 >> 3)) * Dm + (c1 & 7) * 8);
    const bf16x8 vr0 = *(const bf16x8*)(vt + vbase + (size_t)(c0 >> 3) * Sq + kt + (c0 & 7) * 8);
    const bf16x8 vr1 = *(const bf16x8*)(vt + vbase + (size_t)(c1 >> 3) * Sq + kt + (c1 & 7) * 8);
    __syncthreads();  // prior step's K/V reads complete
    *(bf16x8*)&Ks[c0 >> 3][(c0 & 7) * 8] = kr0;
    *(bf16x8*)&Ks[c1 >> 3][(c1 & 7) * 8] = kr1;
    *(bf16x8*)&Vs[c0 >> 3][(c0 & 7) * 8] = vr0;
    *(bf16x8*)&Vs[c1 >> 3][(c1 & 7) * 8] = vr1;
    __syncthreads();

    // S = Q K^T  (raw dot; scale folded into softmax)
    f32x4 s[4];
#pragma unroll
    for (int nt = 0; nt < 4; ++nt) {
      f32x4 acc = {};
      const bf16x8 b0 = *(const bf16x8*)&Ks[nt * 16 + lr][lg * 8];
      const bf16x8 b1 = *(const bf16x8*)&Ks[nt * 16 + lr][32 + lg * 8];
      acc = __builtin_amdgcn_mfma_f32_16x16x32_bf16(aq0, b0, acc, 0, 0, 0);
      acc = __builtin_amdgcn_mfma_f32_16x16x32_bf16(aq1, b1, acc, 0, 0, 0);
      s[nt] = acc;
    }

    // online softmax in base-2 domain; rows lg*4+r, reduce over 16 lanes + nt
#pragma unroll
    for (int r = 0; r < 4; ++r) {
      float tm = fmaxf(fmaxf(s[0][r], s[1][r]), fmaxf(s[2][r], s[3][r]));
      tm = fmaxf(tm, __shfl_xor(tm, 1));
      tm = fmaxf(tm, __shfl_xor(tm, 2));
      tm = fmaxf(tm, __shfl_xor(tm, 4));
      tm = fmaxf(tm, __shfl_xor(tm, 8));
      tm *= SC;
      const float mn = fmaxf(mrow[r], tm);
      const float esc = __builtin_amdgcn_exp2f(mrow[r] - mn);
      mrow[r] = mn;
      float rs = 0.f;
#pragma unroll
      for (int nt = 0; nt < 4; ++nt) {
        const float p = __builtin_amdgcn_exp2f(s[nt][r] * SC - mn);
        s[nt][r] = p;
        rs += p;
      }
      rs += __shfl_xor(rs, 1);
      rs += __shfl_xor(rs, 2);
      rs += __shfl_xor(rs, 4);
      rs += __shfl_xor(rs, 8);
      lrow[r] = lrow[r] * esc + rs;
#pragma unroll
      for (int nt = 0; nt < 4; ++nt) oacc[nt][r] *= esc;
    }

    // P -> bf16 into wave-private LDS (D-layout scatter), re-read as A-frags
#pragma unroll
    for (int r = 0; r < 4; ++r)
#pragma unroll
      for (int nt = 0; nt < 4; ++nt)
        Ps[w][lg * 4 + r][nt * 16 + lr] = f2bf(s[nt][r]);
    const bf16x8 ap0 = *(const bf16x8*)&Ps[w][lr][lg * 8];
    const bf16x8 ap1 = *(const bf16x8*)&Ps[w][lr][32 + lg * 8];

    // O += P V
#pragma unroll
    for (int nt = 0; nt < 4; ++nt) {
      const bf16x8 b0 = *(const bf16x8*)&Vs[nt * 16 + lr][lg * 8];
      const bf16x8 b1 = *(const bf16x8*)&Vs[nt * 16 + lr][32 + lg * 8];
      oacc[nt] = __builtin_amdgcn_mfma_f32_16x16x32_bf16(ap0, b0, oacc[nt], 0, 0, 0);
      oacc[nt] = __builtin_amdgcn_mfma_f32_16x16x32_bf16(ap1, b1, oacc[nt], 0, 0, 0);
    }
  }

  // epilogue: normalize rows, write fp32
#pragma unroll
  for (int r = 0; r < 4; ++r) {
    const float inv = 1.0f / lrow[r];
    const size_t orow = qkbase + (size_t)(q0 + w * 16 + lg * 4 + r) * Dm;
#pragma unroll
    for (int nt = 0; nt < 4; ++nt)
      o[orow + nt * 16 + lr] = oacc[nt][r] * inv;
  }
}

// ---------------------------------------------------------------------------
extern "C" void kernel_launch(void* const* d_in, const int* in_sizes, int n_in,
                              void* d_out, int out_size, void* d_ws, size_t ws_size,
                              hipStream_t stream) {
  (void)in_sizes; (void)n_in; (void)out_size; (void)ws_size;
  const float* x  = (const float*)d_in[0];
  const float* Wq = (const float*)d_in[1];
  const float* bq = (const float*)d_in[2];
  const float* Wk = (const float*)d_in[3];
  const float* bk = (const float*)d_in[4];
  const float* Wv = (const float*)d_in[5];
  const float* bv = (const float*)d_in[6];
  const float* Wo = (const float*)d_in[7];
  const float* bo = (const float*)d_in[8];
  const float* lg = (const float*)d_in[9];
  const float* lb = (const float*)d_in[10];
  float* out = (float*)d_out;

  float* ws = (float*)d_ws;
  const size_t n = (size_t)Mrows * Dm;  // 6.29M elements
  float* xn = ws;                       // fp32 LN output
  float* ab = ws + n;                   // fp32 attention output
  short* qb  = (short*)(ws + 2 * n);    // bf16 Q
  short* kb  = qb + n;                  // bf16 K
  short* vb  = kb + n;                  // bf16 V
  short* vtb = vb + n;                  // bf16 V^T [B,H,64,S]

  ln_kernel<<<Mrows, 256, 0, stream>>>(x, lg, lb, xn);
  const dim3 gg(Mrows / 64, Dm / 64);
  gemm64_kernel<short, false><<<gg, 256, 0, stream>>>(xn, Wq, bq, nullptr, qb);
  gemm64_kernel<short, false><<<gg, 256, 0, stream>>>(xn, Wk, bk, nullptr, kb);
  gemm64_kernel<short, false><<<gg, 256, 0, stream>>>(xn, Wv, bv, nullptr, vb);
  vtrans_kernel<<<dim3(Sq / 64, Hn, Bz), 256, 0, stream>>>(vb, vtb);
  attn_mfma_kernel<<<dim3(Sq / 64, Hn, Bz), 256, 0, stream>>>(qb, kb, vtb, ab);
  gemm64_kernel<float, true><<<gg, 256, 0, stream>>>(ab, Wo, bo, x, out);
}

// Round 3
// 463.982 us; speedup vs baseline: 4.7076x; 2.0102x over previous
//
#include <hip/hip_runtime.h>
#include <hip/hip_bf16.h>
#include <math.h>

// Problem constants (fixed by reference)
constexpr int Bz = 2, Sq = 4096, Dm = 768, Hn = 12, Hd = 64;
constexpr int Mrows = Bz * Sq;  // 8192
constexpr int LDQKV = 2304;     // fused QKV output row stride

typedef short bf16x8 __attribute__((ext_vector_type(8)));
typedef float f32x4 __attribute__((ext_vector_type(4)));

__device__ __forceinline__ short f2bf(float f) {
  unsigned u = __builtin_bit_cast(unsigned, f);
  u += 0x7fffu + ((u >> 16) & 1u);  // round-to-nearest-even
  return (short)(u >> 16);
}

// ---------------------------------------------------------------------------
// Weight prep: W[768][768] f32 (x@W layout) -> Wt[z*768 + n][k] bf16 (n=out col)
// ---------------------------------------------------------------------------
__global__ __launch_bounds__(256) void wprep_kernel(
    const float* __restrict__ Wq, const float* __restrict__ Wk,
    const float* __restrict__ Wv, const float* __restrict__ Wo,
    short* __restrict__ Wt) {
  __shared__ short T[64][72];
  const float* W = blockIdx.z == 0 ? Wq : blockIdx.z == 1 ? Wk
                 : blockIdx.z == 2 ? Wv : Wo;
  const int k0 = blockIdx.x * 64, n0 = blockIdx.y * 64;
  const int t = threadIdx.x;
  const int c4 = (t & 15) * 4, r = t >> 4;
#pragma unroll
  for (int i = 0; i < 4; ++i) {
    const int k = r + i * 16;
    const float4 wv = *(const float4*)(W + (size_t)(k0 + k) * 768 + n0 + c4);
    T[c4 + 0][k] = f2bf(wv.x);
    T[c4 + 1][k] = f2bf(wv.y);
    T[c4 + 2][k] = f2bf(wv.z);
    T[c4 + 3][k] = f2bf(wv.w);
  }
  __syncthreads();
  const int cn = t & 7, nn = t >> 3;
#pragma unroll
  for (int i = 0; i < 2; ++i) {
    const int n = nn + i * 32;
    *(bf16x8*)(Wt + ((size_t)blockIdx.z * 768 + n0 + n) * 768 + k0 + cn * 8) =
        *(const bf16x8*)&T[n][cn * 8];
  }
}

__global__ __launch_bounds__(256) void biaspack_kernel(
    const float* __restrict__ bq, const float* __restrict__ bk,
    const float* __restrict__ bv, const float* __restrict__ bo,
    float* __restrict__ dst) {
  const int j = blockIdx.x * 256 + threadIdx.x;  // 0..3071
  dst[j] = j < 768 ? bq[j] : j < 1536 ? bk[j - 768]
         : j < 2304 ? bv[j - 1536] : bo[j - 2304];
}

// ---------------------------------------------------------------------------
// LayerNorm -> bf16 output. One block per row of 768, 256 threads.
// ---------------------------------------------------------------------------
__global__ __launch_bounds__(256) void ln_kernel(
    const float* __restrict__ x, const float* __restrict__ g,
    const float* __restrict__ b, short* __restrict__ xn) {
  const int row = blockIdx.x;
  const int t = threadIdx.x;
  const float* xr = x + (size_t)row * Dm;
  const float v0 = xr[t], v1 = xr[t + 256], v2 = xr[t + 512];
  float s = v0 + v1 + v2;
  float ss = v0 * v0 + v1 * v1 + v2 * v2;
#pragma unroll
  for (int m = 32; m >= 1; m >>= 1) {
    s += __shfl_xor(s, m);
    ss += __shfl_xor(ss, m);
  }
  __shared__ float red[8];
  const int wid = t >> 6, lane = t & 63;
  if (lane == 0) { red[wid] = s; red[4 + wid] = ss; }
  __syncthreads();
  s = red[0] + red[1] + red[2] + red[3];
  ss = red[4] + red[5] + red[6] + red[7];
  const float mu = s * (1.0f / Dm);
  const float var = ss * (1.0f / Dm) - mu * mu;
  const float rstd = rsqrtf(var + 1e-5f);
  short* xo = xn + (size_t)row * Dm;
  xo[t]       = f2bf((v0 - mu) * rstd * g[t]       + b[t]);
  xo[t + 256] = f2bf((v1 - mu) * rstd * g[t + 256] + b[t + 256]);
  xo[t + 512] = f2bf((v2 - mu) * rstd * g[t + 512] + b[t + 512]);
}

// ---------------------------------------------------------------------------
// bf16 MFMA GEMM, 128x128 tile, BK=64, 4 waves (2x2), 64x64 per wave.
// A[M][ldA] bf16, Bt[N][768] bf16 (row n = output col n).
// XOR-swizzled LDS (linear 128B rows, slot ^= row&7) -> conflict-free b128.
// ---------------------------------------------------------------------------
template <bool OUT_BF16, bool RESID>
__global__ __launch_bounds__(256) void gemm128_kernel(
    const short* __restrict__ A, int ldA, const short* __restrict__ Bt,
    const float* __restrict__ bias, const float* __restrict__ resid,
    void* __restrict__ C, int ldC) {
  __shared__ short As[128 * 64];
  __shared__ short Bs[128 * 64];
  const int m0 = blockIdx.x * 128, n0 = blockIdx.y * 128;
  const int t = threadIdx.x;
  const int w = t >> 6, l = t & 63;
  const int wm = w >> 1, wn = w & 1;
  const int lr = l & 15, lg = l >> 4;
  const int srow = t >> 3, sslot = t & 7;

  f32x4 acc[4][4] = {};

  for (int kt = 0; kt < 768; kt += 64) {
    bf16x8 av[4], bv[4];
#pragma unroll
    for (int it = 0; it < 4; ++it) {
      const int row = it * 32 + srow;
      av[it] = *(const bf16x8*)(A + (size_t)(m0 + row) * ldA + kt + sslot * 8);
      bv[it] = *(const bf16x8*)(Bt + (size_t)(n0 + row) * 768 + kt + sslot * 8);
    }
    __syncthreads();  // prior iteration's frag reads complete
#pragma unroll
    for (int it = 0; it < 4; ++it) {
      const int row = it * 32 + srow;
      const int sidx = row * 64 + ((sslot ^ (row & 7)) * 8);
      *(bf16x8*)&As[sidx] = av[it];
      *(bf16x8*)&Bs[sidx] = bv[it];
    }
    __syncthreads();
#pragma unroll
    for (int ks = 0; ks < 2; ++ks) {
      bf16x8 af[4], bfr[4];
#pragma unroll
      for (int f = 0; f < 4; ++f) {
        const int ar = wm * 64 + f * 16 + lr;
        af[f] = *(const bf16x8*)&As[ar * 64 + (((ks * 4 + lg) ^ (ar & 7)) * 8)];
        const int br = wn * 64 + f * 16 + lr;
        bfr[f] = *(const bf16x8*)&Bs[br * 64 + (((ks * 4 + lg) ^ (br & 7)) * 8)];
      }
      __builtin_amdgcn_s_setprio(1);
#pragma unroll
      for (int mf = 0; mf < 4; ++mf)
#pragma unroll
        for (int nf = 0; nf < 4; ++nf)
          acc[mf][nf] = __builtin_amdgcn_mfma_f32_16x16x32_bf16(
              af[mf], bfr[nf], acc[mf][nf], 0, 0, 0);
      __builtin_amdgcn_s_setprio(0);
    }
  }

  const int colbase = n0 + wn * 64;
  const int rowbase = m0 + wm * 64;
#pragma unroll
  for (int nf = 0; nf < 4; ++nf) {
    const int col = colbase + nf * 16 + lr;
    const float bb = bias[col];
#pragma unroll
    for (int mf = 0; mf < 4; ++mf) {
#pragma unroll
      for (int rr = 0; rr < 4; ++rr) {
        const int row = rowbase + mf * 16 + lg * 4 + rr;
        const float vv = acc[mf][nf][rr] + bb;
        if constexpr (OUT_BF16) {
          ((short*)C)[(size_t)row * ldC + col] = f2bf(vv);
        } else {
          ((float*)C)[(size_t)row * ldC + col] =
              vv + resid[(size_t)row * 768 + col];
        }
      }
    }
  }
}

// ---------------------------------------------------------------------------
// V transpose: qkv V-section [B,S,2304] bf16 -> vt [B,H,64,S] bf16.
// ---------------------------------------------------------------------------
__global__ __launch_bounds__(256) void vtrans_kernel(
    const short* __restrict__ vb, short* __restrict__ vt) {
  __shared__ short T[64][72];
  const int kv0 = blockIdx.x * 64;
  const int h = blockIdx.y, b = blockIdx.z;
  const int t = threadIdx.x;
  const size_t ib = ((size_t)b * Sq) * LDQKV + (size_t)h * Hd;
  const size_t ob = ((size_t)(b * Hn + h) * Hd) * Sq;
#pragma unroll
  for (int cc = 0; cc < 2; ++cc) {
    const int c = t + cc * 256;
    const int row = c >> 3, c8 = c & 7;
    const bf16x8 vv = *(const bf16x8*)(vb + ib + (size_t)(kv0 + row) * LDQKV + c8 * 8);
#pragma unroll
    for (int e = 0; e < 8; ++e) T[c8 * 8 + e][row] = vv[e];
  }
  __syncthreads();
#pragma unroll
  for (int cc = 0; cc < 2; ++cc) {
    const int c = t + cc * 256;
    const int d = c >> 3, c8 = c & 7;
    *(bf16x8*)(vt + ob + (size_t)d * Sq + kv0 + c8 * 8) = *(const bf16x8*)&T[d][c8 * 8];
  }
}

// ---------------------------------------------------------------------------
// Flash attention, bf16 MFMA 16x16x32, fp32 online softmax (base-2 domain).
// 4 waves x 16 Q-rows, K/V tile 64. XOR-swizzled LDS, bf16 output.
// qg,kg: bf16 stride LDQKV head slice. vt: bf16 [B,H,64,S]. o: bf16 [B,S,768].
// ---------------------------------------------------------------------------
__global__ __launch_bounds__(256) void attn_mfma_kernel(
    const short* __restrict__ qg, const short* __restrict__ kg,
    const short* __restrict__ vt, short* __restrict__ o) {
  __shared__ short Ks[64 * 64];     // [kv][d] swizzled
  __shared__ short Vs[64 * 64];     // [d][kv] swizzled
  __shared__ short Ps[4][16 * 64];  // wave-private [qrow][kv] swizzled
  const int q0 = blockIdx.x * 64;
  const int h = blockIdx.y, b = blockIdx.z;
  const size_t qkbase = ((size_t)b * Sq) * LDQKV + (size_t)h * Hd;
  const size_t vbase = ((size_t)(b * Hn + h) * Hd) * Sq;
  const size_t obase = ((size_t)b * Sq) * Dm + (size_t)h * Hd;
  const int t = threadIdx.x;
  const int w = t >> 6, l = t & 63;
  const int lr = l & 15, lg = l >> 4;

  // Q A-fragments hoisted (rows q0 + w*16 + lr)
  bf16x8 aq0, aq1;
  {
    const short* qp = qg + qkbase + (size_t)(q0 + w * 16 + lr) * LDQKV + lg * 8;
    aq0 = *(const bf16x8*)qp;
    aq1 = *(const bf16x8*)(qp + 32);
  }

  float mrow[4] = {-INFINITY, -INFINITY, -INFINITY, -INFINITY};
  float lrow[4] = {0.f, 0.f, 0.f, 0.f};
  f32x4 oacc[4] = {};

  constexpr float SC = 0.18033688011112042f;  // (1/8) * log2(e)

  const int srow = t >> 3, sslot = t & 7;          // c0 = t
  const int srow1 = srow + 32, sslot1 = sslot;     // c1 = t + 256

  for (int kt = 0; kt < Sq; kt += 64) {
    const bf16x8 kr0 = *(const bf16x8*)(kg + qkbase + (size_t)(kt + srow) * LDQKV + sslot * 8);
    const bf16x8 kr1 = *(const bf16x8*)(kg + qkbase + (size_t)(kt + srow1) * LDQKV + sslot1 * 8);
    const bf16x8 vr0 = *(const bf16x8*)(vt + vbase + (size_t)srow * Sq + kt + sslot * 8);
    const bf16x8 vr1 = *(const bf16x8*)(vt + vbase + (size_t)srow1 * Sq + kt + sslot1 * 8);
    __syncthreads();  // prior step's frag reads complete
    *(bf16x8*)&Ks[srow * 64 + ((sslot ^ (srow & 7)) * 8)] = kr0;
    *(bf16x8*)&Ks[srow1 * 64 + ((sslot1 ^ (srow1 & 7)) * 8)] = kr1;
    *(bf16x8*)&Vs[srow * 64 + ((sslot ^ (srow & 7)) * 8)] = vr0;
    *(bf16x8*)&Vs[srow1 * 64 + ((sslot1 ^ (srow1 & 7)) * 8)] = vr1;
    __syncthreads();

    // S = Q K^T
    f32x4 s[4];
    __builtin_amdgcn_s_setprio(1);
#pragma unroll
    for (int nt = 0; nt < 4; ++nt) {
      const int jr = nt * 16 + lr;
      const bf16x8 b0 = *(const bf16x8*)&Ks[jr * 64 + ((lg ^ (jr & 7)) * 8)];
      const bf16x8 b1 = *(const bf16x8*)&Ks[jr * 64 + (((4 + lg) ^ (jr & 7)) * 8)];
      f32x4 acc = {};
      acc = __builtin_amdgcn_mfma_f32_16x16x32_bf16(aq0, b0, acc, 0, 0, 0);
      acc = __builtin_amdgcn_mfma_f32_16x16x32_bf16(aq1, b1, acc, 0, 0, 0);
      s[nt] = acc;
    }
    __builtin_amdgcn_s_setprio(0);

    // online softmax (rows lg*4+r within 16-lane groups)
#pragma unroll
    for (int r = 0; r < 4; ++r) {
      float tm = fmaxf(fmaxf(s[0][r], s[1][r]), fmaxf(s[2][r], s[3][r]));
      tm = fmaxf(tm, __shfl_xor(tm, 1));
      tm = fmaxf(tm, __shfl_xor(tm, 2));
      tm = fmaxf(tm, __shfl_xor(tm, 4));
      tm = fmaxf(tm, __shfl_xor(tm, 8));
      tm *= SC;
      const float mn = fmaxf(mrow[r], tm);
      const float esc = __builtin_amdgcn_exp2f(mrow[r] - mn);
      mrow[r] = mn;
      float rs = 0.f;
#pragma unroll
      for (int nt = 0; nt < 4; ++nt) {
        const float p = __builtin_amdgcn_exp2f(s[nt][r] * SC - mn);
        s[nt][r] = p;
        rs += p;
      }
      rs += __shfl_xor(rs, 1);
      rs += __shfl_xor(rs, 2);
      rs += __shfl_xor(rs, 4);
      rs += __shfl_xor(rs, 8);
      lrow[r] = lrow[r] * esc + rs;
#pragma unroll
      for (int nt = 0; nt < 4; ++nt) oacc[nt][r] *= esc;
    }

    // P -> bf16 into wave-private swizzled LDS, re-read as A-frags
#pragma unroll
    for (int r = 0; r < 4; ++r) {
      const int prow = lg * 4 + r;
#pragma unroll
      for (int nt = 0; nt < 4; ++nt) {
        const int col = nt * 16 + lr;
        const int slot = col >> 3;
        Ps[w][prow * 64 + ((slot ^ (prow & 7)) * 8) + (col & 7)] = f2bf(s[nt][r]);
      }
    }
    const bf16x8 ap0 = *(const bf16x8*)&Ps[w][lr * 64 + ((lg ^ (lr & 7)) * 8)];
    const bf16x8 ap1 = *(const bf16x8*)&Ps[w][lr * 64 + (((4 + lg) ^ (lr & 7)) * 8)];

    // O += P V
    __builtin_amdgcn_s_setprio(1);
#pragma unroll
    for (int nt = 0; nt < 4; ++nt) {
      const int dr = nt * 16 + lr;
      const bf16x8 b0 = *(const bf16x8*)&Vs[dr * 64 + ((lg ^ (dr & 7)) * 8)];
      const bf16x8 b1 = *(const bf16x8*)&Vs[dr * 64 + (((4 + lg) ^ (dr & 7)) * 8)];
      oacc[nt] = __builtin_amdgcn_mfma_f32_16x16x32_bf16(ap0, b0, oacc[nt], 0, 0, 0);
      oacc[nt] = __builtin_amdgcn_mfma_f32_16x16x32_bf16(ap1, b1, oacc[nt], 0, 0, 0);
    }
    __builtin_amdgcn_s_setprio(0);
  }

  // epilogue: normalize, write bf16
#pragma unroll
  for (int r = 0; r < 4; ++r) {
    const float inv = 1.0f / lrow[r];
    short* orow = o + obase + (size_t)(q0 + w * 16 + lg * 4 + r) * Dm;
#pragma unroll
    for (int nt = 0; nt < 4; ++nt)
      orow[nt * 16 + lr] = f2bf(oacc[nt][r] * inv);
  }
}

// ---------------------------------------------------------------------------
extern "C" void kernel_launch(void* const* d_in, const int* in_sizes, int n_in,
                              void* d_out, int out_size, void* d_ws, size_t ws_size,
                              hipStream_t stream) {
  (void)in_sizes; (void)n_in; (void)out_size; (void)ws_size;
  const float* x  = (const float*)d_in[0];
  const float* Wq = (const float*)d_in[1];
  const float* bq = (const float*)d_in[2];
  const float* Wk = (const float*)d_in[3];
  const float* bk = (const float*)d_in[4];
  const float* Wv = (const float*)d_in[5];
  const float* bv = (const float*)d_in[6];
  const float* Wo = (const float*)d_in[7];
  const float* bo = (const float*)d_in[8];
  const float* lg = (const float*)d_in[9];
  const float* lb = (const float*)d_in[10];
  float* out = (float*)d_out;

  const size_t n = (size_t)Mrows * Dm;
  short* ws16 = (short*)d_ws;
  short* xn   = ws16;                             // bf16 LN out      [M][768]
  short* qkv  = xn + n;                           // bf16 QKV         [M][2304]
  short* vt   = qkv + (size_t)Mrows * LDQKV;      // bf16 V^T         [B,H,64,S]
  short* ab   = vt + n;                           // bf16 attn out    [M][768]
  short* Wt   = ab + n;                           // bf16 weights^T   [3072][768]
  float* ball = (float*)(Wt + (size_t)3072 * 768);  // f32 bias      [3072]

  wprep_kernel<<<dim3(12, 12, 4), 256, 0, stream>>>(Wq, Wk, Wv, Wo, Wt);
  biaspack_kernel<<<12, 256, 0, stream>>>(bq, bk, bv, bo, ball);
  ln_kernel<<<Mrows, 256, 0, stream>>>(x, lg, lb, xn);
  gemm128_kernel<true, false><<<dim3(Mrows / 128, LDQKV / 128), 256, 0, stream>>>(
      xn, Dm, Wt, ball, nullptr, qkv, LDQKV);
  vtrans_kernel<<<dim3(Sq / 64, Hn, Bz), 256, 0, stream>>>(qkv + 1536, vt);
  attn_mfma_kernel<<<dim3(Sq / 64, Hn, Bz), 256, 0, stream>>>(qkv, qkv + 768, vt, ab);
  gemm128_kernel<false, true><<<dim3(Mrows / 128, Dm / 128), 256, 0, stream>>>(
      ab, Dm, Wt + (size_t)2304 * 768, ball + 2304, x, out, Dm);
}

// Round 4
// 358.851 us; speedup vs baseline: 6.0867x; 1.2930x over previous
//
#include <hip/hip_runtime.h>
#include <hip/hip_bf16.h>
#include <math.h>

// Problem constants (fixed by reference)
constexpr int Bz = 2, Sq = 4096, Dm = 768, Hn = 12, Hd = 64;
constexpr int Mrows = Bz * Sq;  // 8192
constexpr int LDQKV = 2304;     // fused QKV output row stride

typedef short bf16x8 __attribute__((ext_vector_type(8)));
typedef float f32x4 __attribute__((ext_vector_type(4)));

__device__ __forceinline__ short f2bf(float f) {
  unsigned u = __builtin_bit_cast(unsigned, f);
  u += 0x7fffu + ((u >> 16) & 1u);  // round-to-nearest-even
  return (short)(u >> 16);
}

__device__ __forceinline__ unsigned cvt_pk_bf16(float a, float b) {
  unsigned r;
  asm("v_cvt_pk_bf16_f32 %0, %1, %2" : "=v"(r) : "v"(a), "v"(b));
  return r;  // lo16 = bf16(a), hi16 = bf16(b)
}

// ---------------------------------------------------------------------------
// Weight prep: W[768][768] f32 (x@W layout) -> Wt[z*768 + n][k] bf16 (n=out col)
// ---------------------------------------------------------------------------
__global__ __launch_bounds__(256) void wprep_kernel(
    const float* __restrict__ Wq, const float* __restrict__ Wk,
    const float* __restrict__ Wv, const float* __restrict__ Wo,
    short* __restrict__ Wt) {
  __shared__ short T[64][72];
  const float* W = blockIdx.z == 0 ? Wq : blockIdx.z == 1 ? Wk
                 : blockIdx.z == 2 ? Wv : Wo;
  const int k0 = blockIdx.x * 64, n0 = blockIdx.y * 64;
  const int t = threadIdx.x;
  const int c4 = (t & 15) * 4, r = t >> 4;
#pragma unroll
  for (int i = 0; i < 4; ++i) {
    const int k = r + i * 16;
    const float4 wv = *(const float4*)(W + (size_t)(k0 + k) * 768 + n0 + c4);
    T[c4 + 0][k] = f2bf(wv.x);
    T[c4 + 1][k] = f2bf(wv.y);
    T[c4 + 2][k] = f2bf(wv.z);
    T[c4 + 3][k] = f2bf(wv.w);
  }
  __syncthreads();
  const int cn = t & 7, nn = t >> 3;
#pragma unroll
  for (int i = 0; i < 2; ++i) {
    const int n = nn + i * 32;
    *(bf16x8*)(Wt + ((size_t)blockIdx.z * 768 + n0 + n) * 768 + k0 + cn * 8) =
        *(const bf16x8*)&T[n][cn * 8];
  }
}

__global__ __launch_bounds__(256) void biaspack_kernel(
    const float* __restrict__ bq, const float* __restrict__ bk,
    const float* __restrict__ bv, const float* __restrict__ bo,
    float* __restrict__ dst) {
  const int j = blockIdx.x * 256 + threadIdx.x;  // 0..3071
  dst[j] = j < 768 ? bq[j] : j < 1536 ? bk[j - 768]
         : j < 2304 ? bv[j - 1536] : bo[j - 2304];
}

// ---------------------------------------------------------------------------
// LayerNorm -> bf16 output. One block per row of 768, 256 threads.
// ---------------------------------------------------------------------------
__global__ __launch_bounds__(256) void ln_kernel(
    const float* __restrict__ x, const float* __restrict__ g,
    const float* __restrict__ b, short* __restrict__ xn) {
  const int row = blockIdx.x;
  const int t = threadIdx.x;
  const float* xr = x + (size_t)row * Dm;
  const float v0 = xr[t], v1 = xr[t + 256], v2 = xr[t + 512];
  float s = v0 + v1 + v2;
  float ss = v0 * v0 + v1 * v1 + v2 * v2;
#pragma unroll
  for (int m = 32; m >= 1; m >>= 1) {
    s += __shfl_xor(s, m);
    ss += __shfl_xor(ss, m);
  }
  __shared__ float red[8];
  const int wid = t >> 6, lane = t & 63;
  if (lane == 0) { red[wid] = s; red[4 + wid] = ss; }
  __syncthreads();
  s = red[0] + red[1] + red[2] + red[3];
  ss = red[4] + red[5] + red[6] + red[7];
  const float mu = s * (1.0f / Dm);
  const float var = ss * (1.0f / Dm) - mu * mu;
  const float rstd = rsqrtf(var + 1e-5f);
  short* xo = xn + (size_t)row * Dm;
  xo[t]       = f2bf((v0 - mu) * rstd * g[t]       + b[t]);
  xo[t + 256] = f2bf((v1 - mu) * rstd * g[t + 256] + b[t + 256]);
  xo[t + 512] = f2bf((v2 - mu) * rstd * g[t + 512] + b[t + 512]);
}

// ---------------------------------------------------------------------------
// bf16 MFMA GEMM, 128x128 tile, BK=64, 4 waves (2x2), 64x64 per wave.
// A[M][ldA] bf16, Bt[N][768] bf16 (row n = output col n).
// XOR-swizzled LDS (linear 128B rows, slot ^= row&7) -> conflict-free b128.
// ---------------------------------------------------------------------------
template <bool OUT_BF16, bool RESID>
__global__ __launch_bounds__(256) void gemm128_kernel(
    const short* __restrict__ A, int ldA, const short* __restrict__ Bt,
    const float* __restrict__ bias, const float* __restrict__ resid,
    void* __restrict__ C, int ldC) {
  __shared__ short As[128 * 64];
  __shared__ short Bs[128 * 64];
  const int m0 = blockIdx.x * 128, n0 = blockIdx.y * 128;
  const int t = threadIdx.x;
  const int w = t >> 6, l = t & 63;
  const int wm = w >> 1, wn = w & 1;
  const int lr = l & 15, lg = l >> 4;
  const int srow = t >> 3, sslot = t & 7;

  f32x4 acc[4][4] = {};

  for (int kt = 0; kt < 768; kt += 64) {
    bf16x8 av[4], bv[4];
#pragma unroll
    for (int it = 0; it < 4; ++it) {
      const int row = it * 32 + srow;
      av[it] = *(const bf16x8*)(A + (size_t)(m0 + row) * ldA + kt + sslot * 8);
      bv[it] = *(const bf16x8*)(Bt + (size_t)(n0 + row) * 768 + kt + sslot * 8);
    }
    __syncthreads();  // prior iteration's frag reads complete
#pragma unroll
    for (int it = 0; it < 4; ++it) {
      const int row = it * 32 + srow;
      const int sidx = row * 64 + ((sslot ^ (row & 7)) * 8);
      *(bf16x8*)&As[sidx] = av[it];
      *(bf16x8*)&Bs[sidx] = bv[it];
    }
    __syncthreads();
#pragma unroll
    for (int ks = 0; ks < 2; ++ks) {
      bf16x8 af[4], bfr[4];
#pragma unroll
      for (int f = 0; f < 4; ++f) {
        const int ar = wm * 64 + f * 16 + lr;
        af[f] = *(const bf16x8*)&As[ar * 64 + (((ks * 4 + lg) ^ (ar & 7)) * 8)];
        const int br = wn * 64 + f * 16 + lr;
        bfr[f] = *(const bf16x8*)&Bs[br * 64 + (((ks * 4 + lg) ^ (br & 7)) * 8)];
      }
      __builtin_amdgcn_s_setprio(1);
#pragma unroll
      for (int mf = 0; mf < 4; ++mf)
#pragma unroll
        for (int nf = 0; nf < 4; ++nf)
          acc[mf][nf] = __builtin_amdgcn_mfma_f32_16x16x32_bf16(
              af[mf], bfr[nf], acc[mf][nf], 0, 0, 0);
      __builtin_amdgcn_s_setprio(0);
    }
  }

  const int colbase = n0 + wn * 64;
  const int rowbase = m0 + wm * 64;
#pragma unroll
  for (int nf = 0; nf < 4; ++nf) {
    const int col = colbase + nf * 16 + lr;
    const float bb = bias[col];
#pragma unroll
    for (int mf = 0; mf < 4; ++mf) {
#pragma unroll
      for (int rr = 0; rr < 4; ++rr) {
        const int row = rowbase + mf * 16 + lg * 4 + rr;
        const float vv = acc[mf][nf][rr] + bb;
        if constexpr (OUT_BF16) {
          ((short*)C)[(size_t)row * ldC + col] = f2bf(vv);
        } else {
          ((float*)C)[(size_t)row * ldC + col] =
              vv + resid[(size_t)row * 768 + col];
        }
      }
    }
  }
}

// ---------------------------------------------------------------------------
// V transpose: qkv V-section [B,S,2304] bf16 -> vt [B,H,64,S] bf16.
// ---------------------------------------------------------------------------
__global__ __launch_bounds__(256) void vtrans_kernel(
    const short* __restrict__ vb, short* __restrict__ vt) {
  __shared__ short T[64][72];
  const int kv0 = blockIdx.x * 64;
  const int h = blockIdx.y, b = blockIdx.z;
  const int t = threadIdx.x;
  const size_t ib = ((size_t)b * Sq) * LDQKV + (size_t)h * Hd;
  const size_t ob = ((size_t)(b * Hn + h) * Hd) * Sq;
#pragma unroll
  for (int cc = 0; cc < 2; ++cc) {
    const int c = t + cc * 256;
    const int row = c >> 3, c8 = c & 7;
    const bf16x8 vv = *(const bf16x8*)(vb + ib + (size_t)(kv0 + row) * LDQKV + c8 * 8);
#pragma unroll
    for (int e = 0; e < 8; ++e) T[c8 * 8 + e][row] = vv[e];
  }
  __syncthreads();
#pragma unroll
  for (int cc = 0; cc < 2; ++cc) {
    const int c = t + cc * 256;
    const int d = c >> 3, c8 = c & 7;
    *(bf16x8*)(vt + ob + (size_t)d * Sq + kv0 + c8 * 8) = *(const bf16x8*)&T[d][c8 * 8];
  }
}

// ---------------------------------------------------------------------------
// Flash attention, bf16 MFMA 16x16x32, SWAPPED QK^T (S^T = K·Q^T) so each
// lane owns one q-row lane-locally -> in-register softmax:
//   - lane (lr,lg): q = lr, holds S^T values kv = nt*16 + lg*4 + r
//   - row max: 15 in-lane fmax + shfl_xor(16,32)
//   - row sum: per-lane partial, reduced once in epilogue
//   - P pack: 8 cvt_pk_bf16 + 4 ds_write_b64 + 2 ds_read_b128 (swizzled)
// PV unchanged: A=P (row=q), B=V^T frags; oacc lane: q=lg*4+r, d=nt*16+lr.
// ---------------------------------------------------------------------------
__global__ __launch_bounds__(256) void attn_mfma_kernel(
    const short* __restrict__ qg, const short* __restrict__ kg,
    const short* __restrict__ vt, short* __restrict__ o) {
  __shared__ short Ks[64 * 64];     // [kv][d] swizzled
  __shared__ short Vs[64 * 64];     // [d][kv] swizzled
  __shared__ short Ps[4][16 * 64];  // wave-private [q][kv] swizzled
  const int q0 = blockIdx.x * 64;
  const int h = blockIdx.y, b = blockIdx.z;
  const size_t qkbase = ((size_t)b * Sq) * LDQKV + (size_t)h * Hd;
  const size_t vbase = ((size_t)(b * Hn + h) * Hd) * Sq;
  const size_t obase = ((size_t)b * Sq) * Dm + (size_t)h * Hd;
  const int t = threadIdx.x;
  const int w = t >> 6, l = t & 63;
  const int lr = l & 15, lg = l >> 4;

  // Q fragments (B-operand now; same layout: col=q=lr, k=d=lg*8+e), hoisted
  bf16x8 aq0, aq1;
  {
    const short* qp = qg + qkbase + (size_t)(q0 + w * 16 + lr) * LDQKV + lg * 8;
    aq0 = *(const bf16x8*)qp;
    aq1 = *(const bf16x8*)(qp + 32);
  }

  float mrow = -INFINITY;  // running max for q = lr (scaled domain)
  float lrow = 0.f;        // per-lane PARTIAL denominator for q = lr
  f32x4 oacc[4] = {};      // lane: q = lg*4+r, d = nt*16+lr

  constexpr float SC = 0.18033688011112042f;  // (1/8) * log2(e)

  const int srow = t >> 3, sslot = t & 7;       // c0 = t
  const int srow1 = srow + 32;                  // c1 = t + 256

  for (int kt = 0; kt < Sq; kt += 64) {
    const bf16x8 kr0 = *(const bf16x8*)(kg + qkbase + (size_t)(kt + srow) * LDQKV + sslot * 8);
    const bf16x8 kr1 = *(const bf16x8*)(kg + qkbase + (size_t)(kt + srow1) * LDQKV + sslot * 8);
    const bf16x8 vr0 = *(const bf16x8*)(vt + vbase + (size_t)srow * Sq + kt + sslot * 8);
    const bf16x8 vr1 = *(const bf16x8*)(vt + vbase + (size_t)srow1 * Sq + kt + sslot * 8);
    __syncthreads();  // prior step's frag reads complete
    *(bf16x8*)&Ks[srow * 64 + ((sslot ^ (srow & 7)) * 8)] = kr0;
    *(bf16x8*)&Ks[srow1 * 64 + ((sslot ^ (srow1 & 7)) * 8)] = kr1;
    *(bf16x8*)&Vs[srow * 64 + ((sslot ^ (srow & 7)) * 8)] = vr0;
    *(bf16x8*)&Vs[srow1 * 64 + ((sslot ^ (srow1 & 7)) * 8)] = vr1;
    __syncthreads();

    // S^T = K Q^T : s[nt][r] = S[kv = nt*16+lg*4+r][q = lr]
    f32x4 s[4];
    __builtin_amdgcn_s_setprio(1);
#pragma unroll
    for (int nt = 0; nt < 4; ++nt) {
      const int jr = nt * 16 + lr;
      const bf16x8 k0 = *(const bf16x8*)&Ks[jr * 64 + ((lg ^ (jr & 7)) * 8)];
      const bf16x8 k1 = *(const bf16x8*)&Ks[jr * 64 + (((4 + lg) ^ (jr & 7)) * 8)];
      f32x4 acc = {};
      acc = __builtin_amdgcn_mfma_f32_16x16x32_bf16(k0, aq0, acc, 0, 0, 0);
      acc = __builtin_amdgcn_mfma_f32_16x16x32_bf16(k1, aq1, acc, 0, 0, 0);
      s[nt] = acc;
    }
    __builtin_amdgcn_s_setprio(0);

    // in-register softmax for q = lr
    float t0 = fmaxf(fmaxf(s[0][0], s[0][1]), fmaxf(s[0][2], s[0][3]));
    float t1 = fmaxf(fmaxf(s[1][0], s[1][1]), fmaxf(s[1][2], s[1][3]));
    float t2 = fmaxf(fmaxf(s[2][0], s[2][1]), fmaxf(s[2][2], s[2][3]));
    float t3 = fmaxf(fmaxf(s[3][0], s[3][1]), fmaxf(s[3][2], s[3][3]));
    float tm = fmaxf(fmaxf(t0, t1), fmaxf(t2, t3));
    tm = fmaxf(tm, __shfl_xor(tm, 16));
    tm = fmaxf(tm, __shfl_xor(tm, 32));
    const float mn = fmaxf(mrow, tm * SC);
    const float esc = __builtin_amdgcn_exp2f(mrow - mn);
    mrow = mn;
    const float negmn = -mn;
    float psum = 0.f;
#pragma unroll
    for (int nt = 0; nt < 4; ++nt)
#pragma unroll
      for (int r = 0; r < 4; ++r) {
        const float p = __builtin_amdgcn_exp2f(fmaf(s[nt][r], SC, negmn));
        s[nt][r] = p;
        psum += p;
      }
    lrow = lrow * esc + psum;  // partial over this lane's kv quarter

    // broadcast esc to oacc rows (q = lg*4+r lives at lane lg*4+r)
    float escq[4];
#pragma unroll
    for (int r = 0; r < 4; ++r) escq[r] = __shfl(esc, lg * 4 + r);
#pragma unroll
    for (int nt = 0; nt < 4; ++nt)
#pragma unroll
      for (int r = 0; r < 4; ++r) oacc[nt][r] *= escq[r];

    // P pack: r-pairs are kv-adjacent -> cvt_pk + one b64 write per nt
#pragma unroll
    for (int nt = 0; nt < 4; ++nt) {
      uint2 pk;
      pk.x = cvt_pk_bf16(s[nt][0], s[nt][1]);
      pk.y = cvt_pk_bf16(s[nt][2], s[nt][3]);
      const int slot = (nt * 2 + (lg >> 1)) ^ (lr & 7);
      *(uint2*)&Ps[w][lr * 64 + slot * 8 + (lg & 1) * 4] = pk;
    }
    const bf16x8 ap0 = *(const bf16x8*)&Ps[w][lr * 64 + ((lg ^ (lr & 7)) * 8)];
    const bf16x8 ap1 = *(const bf16x8*)&Ps[w][lr * 64 + (((4 + lg) ^ (lr & 7)) * 8)];

    // O += P V
    __builtin_amdgcn_s_setprio(1);
#pragma unroll
    for (int nt = 0; nt < 4; ++nt) {
      const int dr = nt * 16 + lr;
      const bf16x8 b0 = *(const bf16x8*)&Vs[dr * 64 + ((lg ^ (dr & 7)) * 8)];
      const bf16x8 b1 = *(const bf16x8*)&Vs[dr * 64 + (((4 + lg) ^ (dr & 7)) * 8)];
      oacc[nt] = __builtin_amdgcn_mfma_f32_16x16x32_bf16(ap0, b0, oacc[nt], 0, 0, 0);
      oacc[nt] = __builtin_amdgcn_mfma_f32_16x16x32_bf16(ap1, b1, oacc[nt], 0, 0, 0);
    }
    __builtin_amdgcn_s_setprio(0);
  }

  // epilogue: reduce l across the 4 kv-quarter lanes, broadcast inv, write
  float lt = lrow + __shfl_xor(lrow, 16);
  lt += __shfl_xor(lt, 32);
  const float inv = 1.0f / lt;  // valid per lane for q = lr
  float invq[4];
#pragma unroll
  for (int r = 0; r < 4; ++r) invq[r] = __shfl(inv, lg * 4 + r);
#pragma unroll
  for (int r = 0; r < 4; ++r) {
    short* orow = o + obase + (size_t)(q0 + w * 16 + lg * 4 + r) * Dm;
#pragma unroll
    for (int nt = 0; nt < 4; ++nt)
      orow[nt * 16 + lr] = f2bf(oacc[nt][r] * invq[r]);
  }
}

// ---------------------------------------------------------------------------
extern "C" void kernel_launch(void* const* d_in, const int* in_sizes, int n_in,
                              void* d_out, int out_size, void* d_ws, size_t ws_size,
                              hipStream_t stream) {
  (void)in_sizes; (void)n_in; (void)out_size; (void)ws_size;
  const float* x  = (const float*)d_in[0];
  const float* Wq = (const float*)d_in[1];
  const float* bq = (const float*)d_in[2];
  const float* Wk = (const float*)d_in[3];
  const float* bk = (const float*)d_in[4];
  const float* Wv = (const float*)d_in[5];
  const float* bv = (const float*)d_in[6];
  const float* Wo = (const float*)d_in[7];
  const float* bo = (const float*)d_in[8];
  const float* lg = (const float*)d_in[9];
  const float* lb = (const float*)d_in[10];
  float* out = (float*)d_out;

  const size_t n = (size_t)Mrows * Dm;
  short* ws16 = (short*)d_ws;
  short* xn   = ws16;                             // bf16 LN out      [M][768]
  short* qkv  = xn + n;                           // bf16 QKV         [M][2304]
  short* vt   = qkv + (size_t)Mrows * LDQKV;      // bf16 V^T         [B,H,64,S]
  short* ab   = vt + n;                           // bf16 attn out    [M][768]
  short* Wt   = ab + n;                           // bf16 weights^T   [3072][768]
  float* ball = (float*)(Wt + (size_t)3072 * 768);  // f32 bias      [3072]

  wprep_kernel<<<dim3(12, 12, 4), 256, 0, stream>>>(Wq, Wk, Wv, Wo, Wt);
  biaspack_kernel<<<12, 256, 0, stream>>>(bq, bk, bv, bo, ball);
  ln_kernel<<<Mrows, 256, 0, stream>>>(x, lg, lb, xn);
  gemm128_kernel<true, false><<<dim3(Mrows / 128, LDQKV / 128), 256, 0, stream>>>(
      xn, Dm, Wt, ball, nullptr, qkv, LDQKV);
  vtrans_kernel<<<dim3(Sq / 64, Hn, Bz), 256, 0, stream>>>(qkv + 1536, vt);
  attn_mfma_kernel<<<dim3(Sq / 64, Hn, Bz), 256, 0, stream>>>(qkv, qkv + 768, vt, ab);
  gemm128_kernel<false, true><<<dim3(Mrows / 128, Dm / 128), 256, 0, stream>>>(
      ab, Dm, Wt + (size_t)2304 * 768, ball + 2304, x, out, Dm);
}